// Round 11
// baseline (172.135 us; speedup 1.0000x reference)
//
#include <hip/hip_runtime.h>
#include <hip/hip_bf16.h>
#include <cstdint>

#define D_MODEL 128
#define N_HEADS 8
#define HEAD_DIM 16

typedef __attribute__((ext_vector_type(8))) short bf16x8;
typedef __attribute__((ext_vector_type(4))) float f32x4;

static __device__ __forceinline__ float b2f(unsigned short u) {
  unsigned int x = ((unsigned int)u) << 16;
  return __builtin_bit_cast(float, x);
}
static __device__ __forceinline__ unsigned short f2b(float f) {
  __hip_bfloat16 h = __float2bfloat16(f);   // RNE
  return __builtin_bit_cast(unsigned short, h);
}

// ---------------------------------------------------------------------------
// fp32 -> bf16 conversion of the three 128x128 W matrices only (tiny).
// ---------------------------------------------------------------------------
__global__ __launch_bounds__(256) void cvtw_kernel(
    const float* __restrict__ Wq, const float* __restrict__ Wk,
    const float* __restrict__ Wv, unsigned short* __restrict__ Wb)
{
  const int wb = blockIdx.x;           // 24 blocks: 8 per matrix
  const int m  = wb >> 3;
  const float* src = (m == 0) ? Wq : (m == 1) ? Wk : Wv;
  unsigned short* dst = Wb + (size_t)m * 16384;
  const int base = ((wb & 7) * 256 + threadIdx.x) * 8;
  const float4 a = reinterpret_cast<const float4*>(src + base)[0];
  const float4 c = reinterpret_cast<const float4*>(src + base)[1];
  unsigned short tmp[8];
  tmp[0] = f2b(a.x); tmp[1] = f2b(a.y); tmp[2] = f2b(a.z); tmp[3] = f2b(a.w);
  tmp[4] = f2b(c.x); tmp[5] = f2b(c.y); tmp[6] = f2b(c.z); tmp[7] = f2b(c.w);
  reinterpret_cast<uint4*>(dst + base)[0] = *reinterpret_cast<uint4*>(tmp);
}

// ---------------------------------------------------------------------------
// MFMA QKV: O[n][j] = sum_k X[n][k] * W[j][k] + b[j].  (unchanged, round 8)
// ---------------------------------------------------------------------------
__global__ __launch_bounds__(128) void qkv_mfma(
    const float* __restrict__ X, const unsigned short* __restrict__ Wb,
    const float* __restrict__ bq, const float* __restrict__ bk,
    const float* __restrict__ bv,
    unsigned short* __restrict__ Qo, unsigned short* __restrict__ Ko,
    unsigned short* __restrict__ Vo, int N)
{
  __shared__ unsigned short Wl[128 * 128];   // 32 KB, restaged per m
  const int t    = threadIdx.x;
  const int wave = t >> 6;
  const int l    = t & 63;
  const int lr   = l & 15;
  const int lg   = l >> 4;
  const int nw   = blockIdx.x * 64 + wave * 32;   // first node of this wave

  bf16x8 a[2][4];
  #pragma unroll
  for (int ng = 0; ng < 2; ++ng) {
    const int arow = nw + ng * 16 + lr;
    if (arow < N) {
      const float* xp = X + (size_t)arow * D_MODEL + lg * 8;
      #pragma unroll
      for (int ks = 0; ks < 4; ++ks) {
        const float4 f0 = reinterpret_cast<const float4*>(xp + ks * 32)[0];
        const float4 f1 = reinterpret_cast<const float4*>(xp + ks * 32)[1];
        unsigned short tm[8];
        tm[0] = f2b(f0.x); tm[1] = f2b(f0.y); tm[2] = f2b(f0.z); tm[3] = f2b(f0.w);
        tm[4] = f2b(f1.x); tm[5] = f2b(f1.y); tm[6] = f2b(f1.z); tm[7] = f2b(f1.w);
        a[ng][ks] = *reinterpret_cast<bf16x8*>(tm);
      }
    } else {
      #pragma unroll
      for (int ks = 0; ks < 4; ++ks) a[ng][ks] = bf16x8{0,0,0,0,0,0,0,0};
    }
  }

  const float* biases[3] = {bq, bk, bv};
  unsigned short* outs[3] = {Qo, Ko, Vo};

  #pragma unroll 1
  for (int m = 0; m < 3; ++m) {
    __syncthreads();
    {
      const uint4* wsrc = reinterpret_cast<const uint4*>(Wb + (size_t)m * 16384);
      uint4* wl4 = reinterpret_cast<uint4*>(Wl);
      #pragma unroll
      for (int i = 0; i < 16; ++i) {
        const int cg = i * 128 + t;          // global chunk id, 0..2047
        const int r  = cg >> 4;
        const int j  = cg & 15;
        wl4[r * 16 + (j ^ (r & 7))] = wsrc[cg];
      }
    }
    __syncthreads();

    unsigned short* __restrict__ O = outs[m];
    const float* __restrict__ bias = biases[m];
    float bias8[8];
    #pragma unroll
    for (int c = 0; c < 8; ++c) bias8[c] = bias[c * 16 + lr];

    #pragma unroll
    for (int c = 0; c < 8; ++c) {
      const int row = c * 16 + lr;
      bf16x8 w[4];
      #pragma unroll
      for (int ks = 0; ks < 4; ++ks) {
        const int j = ks * 4 + lg;
        w[ks] = *reinterpret_cast<const bf16x8*>(
            Wl + ((row * 16 + (j ^ (row & 7))) * 8));
      }
      #pragma unroll
      for (int ng = 0; ng < 2; ++ng) {
        f32x4 acc = {bias8[c], bias8[c], bias8[c], bias8[c]};
        #pragma unroll
        for (int ks = 0; ks < 4; ++ks)
          acc = __builtin_amdgcn_mfma_f32_16x16x32_bf16(a[ng][ks], w[ks], acc, 0, 0, 0);
        #pragma unroll
        for (int r = 0; r < 4; ++r) {
          const int orow = nw + ng * 16 + lg * 4 + r;
          if (orow < N) O[(size_t)orow * D_MODEL + c * 16 + lr] = f2b(acc[r]);
        }
      }
    }
  }
}

// ---------------------------------------------------------------------------
// CSR build: histogram -> hierarchical scan -> scatter   (unchanged)
// ---------------------------------------------------------------------------
__global__ __launch_bounds__(256) void hist_kernel(
    const int* __restrict__ rows, int* __restrict__ cnt, int E)
{
  const int e = blockIdx.x * 256 + threadIdx.x;
  if (e < E) atomicAdd(&cnt[rows[e]], 1);
}

__global__ __launch_bounds__(256) void partial_kernel(
    const int* __restrict__ cnt, int* __restrict__ bsum, int N)
{
  __shared__ int wsum[4];
  const int t = threadIdx.x;
  const int base = blockIdx.x * 1024 + t * 4;
  int s = 0;
  #pragma unroll
  for (int i = 0; i < 4; ++i)
    if (base + i < N) s += cnt[base + i];
  #pragma unroll
  for (int off = 32; off > 0; off >>= 1) s += __shfl_xor(s, off, 64);
  if ((t & 63) == 0) wsum[t >> 6] = s;
  __syncthreads();
  if (t == 0) bsum[blockIdx.x] = wsum[0] + wsum[1] + wsum[2] + wsum[3];
}

__global__ __launch_bounds__(256) void scansums_kernel(
    const int* __restrict__ bsum, int* __restrict__ boff, int nb)
{
  __shared__ int p[256];
  __shared__ int carry_s;
  const int t = threadIdx.x;
  if (t == 0) carry_s = 0;
  __syncthreads();
  for (int c0 = 0; c0 < nb; c0 += 256) {
    const int v = (c0 + t < nb) ? bsum[c0 + t] : 0;
    p[t] = v;
    __syncthreads();
    for (int off = 1; off < 256; off <<= 1) {
      const int other = (t >= off) ? p[t - off] : 0;
      __syncthreads();
      p[t] += other;
      __syncthreads();
    }
    const int carry = carry_s;
    if (c0 + t < nb) boff[c0 + t] = carry + p[t] - v;
    __syncthreads();
    if (t == 0) carry_s = carry + p[255];
    __syncthreads();
  }
}

__global__ __launch_bounds__(256) void emit_kernel(
    const int* __restrict__ cnt, const int* __restrict__ boff,
    int* __restrict__ row_ptr, int* __restrict__ row_cur, int N, int E)
{
  __shared__ int psum[256];
  const int t = threadIdx.x;
  const int base = blockIdx.x * 1024 + t * 4;
  int v[4];
  #pragma unroll
  for (int i = 0; i < 4; ++i)
    v[i] = (base + i < N) ? cnt[base + i] : 0;
  const int local = v[0] + v[1] + v[2] + v[3];
  psum[t] = local;
  __syncthreads();
  for (int off = 1; off < 256; off <<= 1) {
    const int other = (t >= off) ? psum[t - off] : 0;
    __syncthreads();
    psum[t] += other;
    __syncthreads();
  }
  int pre = boff[blockIdx.x] + psum[t] - local;
  #pragma unroll
  for (int i = 0; i < 4; ++i) {
    const int idx = base + i;
    if (idx < N) {
      row_ptr[idx] = pre;
      row_cur[idx] = pre;
      pre += v[i];
    }
  }
  if (blockIdx.x == 0 && t == 0) row_ptr[N] = E;
}

__global__ __launch_bounds__(256) void scatter_kernel(
    const int* __restrict__ rows, const int* __restrict__ cols,
    int* __restrict__ row_cur, int* __restrict__ csr_cols, int E)
{
  const int e = blockIdx.x * 256 + threadIdx.x;
  if (e >= E) return;
  const int pos = atomicAdd(&row_cur[rows[e]], 1);
  csr_cols[pos] = cols[e];
}

// ---------------------------------------------------------------------------
// Fused per-node attention + residual + LayerNorm. bf16 Q/K/V, fp32 math.
// One wave per node, edges in chunks of 8.
// Lane l = (head h = l>>3, edge slot g = l&7). Per chunk, lane computes its
// edge's head-h score in-lane AND accumulates ea * V[c][h*16+i] into 16
// per-lane registers — numerator partials over edge subsets are legal since
// the softmax denominator is node-uniform per head. NO LDS, NO phase 2.
// Once per node: butterfly-reduce (offsets 1,2,4) across same-head lanes,
// then an unrolled cndmask select extracts lane l's 2 output dims.
// ---------------------------------------------------------------------------
__global__ __launch_bounds__(256) void fused_kernel(
    const unsigned short* __restrict__ Q, const unsigned short* __restrict__ K,
    const unsigned short* __restrict__ V, const float* __restrict__ X,
    const int* __restrict__ row_ptr, const int* __restrict__ csr_cols,
    const float* __restrict__ gamma, const float* __restrict__ beta,
    float* __restrict__ out, int N)
{
  const int n = blockIdx.x * 4 + (threadIdx.x >> 6);
  if (n >= N) return;
  const int l = threadIdx.x & 63;
  const int h = l >> 3;    // head owned by this lane
  const int g = l & 7;     // edge slot within chunk

  // Q head-h dims as fp32 (broadcast across the 8 g-lanes of this head)
  float qf[16];
  {
    const unsigned short* qp = Q + (size_t)n * D_MODEL + h * HEAD_DIM;
    const bf16x8 q0 = *reinterpret_cast<const bf16x8*>(qp);
    const bf16x8 q1 = *reinterpret_cast<const bf16x8*>(qp + 8);
    #pragma unroll
    for (int i = 0; i < 8; ++i) {
      qf[i]     = b2f((unsigned short)q0[i]);
      qf[8 + i] = b2f((unsigned short)q1[i]);
    }
  }

  float acc[16];
  #pragma unroll
  for (int i = 0; i < 16; ++i) acc[i] = 0.f;
  float dlane = 0.f;

  const int e0 = row_ptr[n];
  const int e1 = row_ptr[n + 1];

  // 1-deep csr prefetch (shortens per-chunk chain to the K/V gather)
  int cA = 0;
  if (e0 < e1) {
    const int eg = e0 + g;
    cA = (eg < e1) ? csr_cols[eg] : 0;
  }

  for (int eb = e0; eb < e1; eb += 8) {
    const bool valid = (eb + g) < e1;
    const int  c     = cA;
    {
      const int eg2 = eb + 8 + g;
      cA = (eg2 < e1) ? csr_cols[eg2] : 0;
    }

    const unsigned short* kp = K + (size_t)c * D_MODEL + h * HEAD_DIM;
    const unsigned short* vp = V + (size_t)c * D_MODEL + h * HEAD_DIM;
    const bf16x8 k0 = *reinterpret_cast<const bf16x8*>(kp);
    const bf16x8 k1 = *reinterpret_cast<const bf16x8*>(kp + 8);
    const bf16x8 v0 = *reinterpret_cast<const bf16x8*>(vp);
    const bf16x8 v1 = *reinterpret_cast<const bf16x8*>(vp + 8);

    float s = 0.f;
    #pragma unroll
    for (int i = 0; i < 8; ++i) {
      s = fmaf(qf[i],     b2f((unsigned short)k0[i]), s);
      s = fmaf(qf[8 + i], b2f((unsigned short)k1[i]), s);
    }
    s *= 0.25f;                         // 1/sqrt(16)
    s = fminf(fmaxf(s, -10.f), 10.f);
    const float ea = valid ? __expf(s) : 0.f;
    dlane += ea;

    #pragma unroll
    for (int i = 0; i < 8; ++i) {
      acc[i]     = fmaf(ea, b2f((unsigned short)v0[i]), acc[i]);
      acc[8 + i] = fmaf(ea, b2f((unsigned short)v1[i]), acc[8 + i]);
    }
  }

  // reduce numerator + denominator across the 8 edge-slot lanes of each head
  #pragma unroll
  for (int off = 1; off <= 4; off <<= 1) {
    dlane += __shfl_xor(dlane, off, 64);
    #pragma unroll
    for (int i = 0; i < 16; ++i) acc[i] += __shfl_xor(acc[i], off, 64);
  }

  // lane l outputs dims {2l, 2l+1} = head h, local dims {2g, 2g+1}
  float num0 = acc[0], num1 = acc[1];
  #pragma unroll
  for (int j = 1; j < 8; ++j) {
    if (g == j) { num0 = acc[2 * j]; num1 = acc[2 * j + 1]; }
  }

  const float inv = 1.f / (dlane + 1e-8f);
  const float2 x = reinterpret_cast<const float2*>(X + (size_t)n * D_MODEL)[l];
  const float a0 = num0 * inv + x.x;
  const float a1 = num1 * inv + x.y;

  float sm = a0 + a1;
  float ss = a0 * a0 + a1 * a1;
  #pragma unroll
  for (int off = 32; off > 0; off >>= 1) {
    sm += __shfl_xor(sm, off, 64);
    ss += __shfl_xor(ss, off, 64);
  }
  const float mean = sm * (1.f / 128.f);
  const float var  = ss * (1.f / 128.f) - mean * mean;
  const float rs   = rsqrtf(var + 1e-6f);
  const float2 gm = reinterpret_cast<const float2*>(gamma)[l];
  const float2 bt = reinterpret_cast<const float2*>(beta)[l];
  float2 o;
  o.x = (a0 - mean) * rs * gm.x + bt.x;
  o.y = (a1 - mean) * rs * gm.y + bt.y;
  reinterpret_cast<float2*>(out + (size_t)n * D_MODEL)[l] = o;
}

// ---------------------------------------------------------------------------
extern "C" void kernel_launch(void* const* d_in, const int* in_sizes, int n_in,
                              void* d_out, int out_size, void* d_ws, size_t ws_size,
                              hipStream_t stream)
{
  const float* X     = (const float*)d_in[0];
  const int*   ei    = (const int*)  d_in[1];
  const float* Wq    = (const float*)d_in[2];
  const float* bq    = (const float*)d_in[3];
  const float* Wk    = (const float*)d_in[4];
  const float* bk    = (const float*)d_in[5];
  const float* Wv    = (const float*)d_in[6];
  const float* bv    = (const float*)d_in[7];
  const float* gamma = (const float*)d_in[8];
  const float* beta  = (const float*)d_in[9];

  const int N = in_sizes[0] / D_MODEL;
  const int E = in_sizes[1] / 2;
  const int* rows = ei;
  const int* cols = ei + E;

  const size_t nd = (size_t)N * D_MODEL;
  unsigned short* Wb = (unsigned short*)d_ws;
  unsigned short* Qb = Wb + 3 * 16384;
  unsigned short* Kb = Qb + nd;
  unsigned short* Vb = Kb + nd;
  int* row_cnt  = (int*)(Vb + nd);
  int* row_ptr  = row_cnt + N;
  int* row_cur  = row_ptr + N + 1;
  int* csr_cols = row_cur + N;
  int* bsum     = csr_cols + E;
  int* boff     = bsum + ((N + 1023) / 1024) + 1;

  const int nb = (N + 1023) / 1024;

  hipMemsetAsync(row_cnt, 0, (size_t)N * sizeof(int), stream);

  cvtw_kernel<<<24, 256, 0, stream>>>(Wq, Wk, Wv, Wb);

  hist_kernel<<<(E + 255) / 256, 256, 0, stream>>>(rows, row_cnt, E);
  partial_kernel<<<nb, 256, 0, stream>>>(row_cnt, bsum, N);
  scansums_kernel<<<1, 256, 0, stream>>>(bsum, boff, nb);
  emit_kernel<<<nb, 256, 0, stream>>>(row_cnt, boff, row_ptr, row_cur, N, E);
  scatter_kernel<<<(E + 255) / 256, 256, 0, stream>>>(rows, cols, row_cur, csr_cols, E);

  qkv_mfma<<<(N + 63) / 64, 128, 0, stream>>>(
      X, Wb, bq, bk, bv, Qb, Kb, Vb, N);

  fused_kernel<<<(N + 3) / 4, 256, 0, stream>>>(
      Qb, Kb, Vb, X, row_ptr, csr_cols, gamma, beta, (float*)d_out, N);
}

// Round 12
// 158.114 us; speedup vs baseline: 1.0887x; 1.0887x over previous
//
#include <hip/hip_runtime.h>
#include <hip/hip_bf16.h>
#include <cstdint>

#define D_MODEL 128
#define N_HEADS 8
#define HEAD_DIM 16

typedef __attribute__((ext_vector_type(8))) short bf16x8;
typedef __attribute__((ext_vector_type(4))) float f32x4;

static __device__ __forceinline__ float b2f(unsigned short u) {
  unsigned int x = ((unsigned int)u) << 16;
  return __builtin_bit_cast(float, x);
}
static __device__ __forceinline__ unsigned short f2b(float f) {
  __hip_bfloat16 h = __float2bfloat16(f);   // RNE
  return __builtin_bit_cast(unsigned short, h);
}

// ---------------------------------------------------------------------------
// fp32 -> bf16 conversion of the three 128x128 W matrices only (tiny).
// ---------------------------------------------------------------------------
__global__ __launch_bounds__(256) void cvtw_kernel(
    const float* __restrict__ Wq, const float* __restrict__ Wk,
    const float* __restrict__ Wv, unsigned short* __restrict__ Wb)
{
  const int wb = blockIdx.x;           // 24 blocks: 8 per matrix
  const int m  = wb >> 3;
  const float* src = (m == 0) ? Wq : (m == 1) ? Wk : Wv;
  unsigned short* dst = Wb + (size_t)m * 16384;
  const int base = ((wb & 7) * 256 + threadIdx.x) * 8;
  const float4 a = reinterpret_cast<const float4*>(src + base)[0];
  const float4 c = reinterpret_cast<const float4*>(src + base)[1];
  unsigned short tmp[8];
  tmp[0] = f2b(a.x); tmp[1] = f2b(a.y); tmp[2] = f2b(a.z); tmp[3] = f2b(a.w);
  tmp[4] = f2b(c.x); tmp[5] = f2b(c.y); tmp[6] = f2b(c.z); tmp[7] = f2b(c.w);
  reinterpret_cast<uint4*>(dst + base)[0] = *reinterpret_cast<uint4*>(tmp);
}

// ---------------------------------------------------------------------------
// MFMA QKV: O[n][j] = sum_k X[n][k] * W[j][k] + b[j].
// 4 waves/block, 128 nodes/block (wave = 32 nodes as 2 x 16-node groups).
// Per m: W staged once into LDS (32 KB, XOR-swizzled; 8 uint4/thread),
// amortized over 128 nodes; c-loop fully unrolled, hot loop is LDS-only.
// Occupancy: 32 KB LDS -> 5 blocks/CU = 20 waves/CU.
// ---------------------------------------------------------------------------
__global__ __launch_bounds__(256) void qkv_mfma(
    const float* __restrict__ X, const unsigned short* __restrict__ Wb,
    const float* __restrict__ bq, const float* __restrict__ bk,
    const float* __restrict__ bv,
    unsigned short* __restrict__ Qo, unsigned short* __restrict__ Ko,
    unsigned short* __restrict__ Vo, int N)
{
  __shared__ unsigned short Wl[128 * 128];   // 32 KB, restaged per m
  const int t    = threadIdx.x;
  const int wave = t >> 6;
  const int l    = t & 63;
  const int lr   = l & 15;
  const int lg   = l >> 4;
  const int nw   = blockIdx.x * 128 + wave * 32;  // first node of this wave

  bf16x8 a[2][4];
  #pragma unroll
  for (int ng = 0; ng < 2; ++ng) {
    const int arow = nw + ng * 16 + lr;
    if (arow < N) {
      const float* xp = X + (size_t)arow * D_MODEL + lg * 8;
      #pragma unroll
      for (int ks = 0; ks < 4; ++ks) {
        const float4 f0 = reinterpret_cast<const float4*>(xp + ks * 32)[0];
        const float4 f1 = reinterpret_cast<const float4*>(xp + ks * 32)[1];
        unsigned short tm[8];
        tm[0] = f2b(f0.x); tm[1] = f2b(f0.y); tm[2] = f2b(f0.z); tm[3] = f2b(f0.w);
        tm[4] = f2b(f1.x); tm[5] = f2b(f1.y); tm[6] = f2b(f1.z); tm[7] = f2b(f1.w);
        a[ng][ks] = *reinterpret_cast<bf16x8*>(tm);
      }
    } else {
      #pragma unroll
      for (int ks = 0; ks < 4; ++ks) a[ng][ks] = bf16x8{0,0,0,0,0,0,0,0};
    }
  }

  const float* biases[3] = {bq, bk, bv};
  unsigned short* outs[3] = {Qo, Ko, Vo};

  #pragma unroll 1
  for (int m = 0; m < 3; ++m) {
    __syncthreads();   // previous m's reads complete before restage
    // stage W[m]: 32768 B = 2048 uint4 chunks; 8 chunks/thread, coalesced
    {
      const uint4* wsrc = reinterpret_cast<const uint4*>(Wb + (size_t)m * 16384);
      uint4* wl4 = reinterpret_cast<uint4*>(Wl);
      #pragma unroll
      for (int i = 0; i < 8; ++i) {
        const int cg = i * 256 + t;          // global chunk id, 0..2047
        const int r  = cg >> 4;              // W row (output col), 0..127
        const int j  = cg & 15;              // 16B chunk within row
        wl4[r * 16 + (j ^ (r & 7))] = wsrc[cg];
      }
    }
    __syncthreads();

    unsigned short* __restrict__ O = outs[m];
    const float* __restrict__ bias = biases[m];
    float bias8[8];
    #pragma unroll
    for (int c = 0; c < 8; ++c) bias8[c] = bias[c * 16 + lr];

    #pragma unroll
    for (int c = 0; c < 8; ++c) {
      const int row = c * 16 + lr;
      bf16x8 w[4];
      #pragma unroll
      for (int ks = 0; ks < 4; ++ks) {
        const int j = ks * 4 + lg;
        w[ks] = *reinterpret_cast<const bf16x8*>(
            Wl + ((row * 16 + (j ^ (row & 7))) * 8));
      }
      #pragma unroll
      for (int ng = 0; ng < 2; ++ng) {
        f32x4 acc = {bias8[c], bias8[c], bias8[c], bias8[c]};
        #pragma unroll
        for (int ks = 0; ks < 4; ++ks)
          acc = __builtin_amdgcn_mfma_f32_16x16x32_bf16(a[ng][ks], w[ks], acc, 0, 0, 0);
        #pragma unroll
        for (int r = 0; r < 4; ++r) {
          const int orow = nw + ng * 16 + lg * 4 + r;
          if (orow < N) O[(size_t)orow * D_MODEL + c * 16 + lr] = f2b(acc[r]);
        }
      }
    }
  }
}

// ---------------------------------------------------------------------------
// CSR build: histogram -> hierarchical scan -> scatter   (unchanged)
// ---------------------------------------------------------------------------
__global__ __launch_bounds__(256) void hist_kernel(
    const int* __restrict__ rows, int* __restrict__ cnt, int E)
{
  const int e = blockIdx.x * 256 + threadIdx.x;
  if (e < E) atomicAdd(&cnt[rows[e]], 1);
}

__global__ __launch_bounds__(256) void partial_kernel(
    const int* __restrict__ cnt, int* __restrict__ bsum, int N)
{
  __shared__ int wsum[4];
  const int t = threadIdx.x;
  const int base = blockIdx.x * 1024 + t * 4;
  int s = 0;
  #pragma unroll
  for (int i = 0; i < 4; ++i)
    if (base + i < N) s += cnt[base + i];
  #pragma unroll
  for (int off = 32; off > 0; off >>= 1) s += __shfl_xor(s, off, 64);
  if ((t & 63) == 0) wsum[t >> 6] = s;
  __syncthreads();
  if (t == 0) bsum[blockIdx.x] = wsum[0] + wsum[1] + wsum[2] + wsum[3];
}

__global__ __launch_bounds__(256) void scansums_kernel(
    const int* __restrict__ bsum, int* __restrict__ boff, int nb)
{
  __shared__ int p[256];
  __shared__ int carry_s;
  const int t = threadIdx.x;
  if (t == 0) carry_s = 0;
  __syncthreads();
  for (int c0 = 0; c0 < nb; c0 += 256) {
    const int v = (c0 + t < nb) ? bsum[c0 + t] : 0;
    p[t] = v;
    __syncthreads();
    for (int off = 1; off < 256; off <<= 1) {
      const int other = (t >= off) ? p[t - off] : 0;
      __syncthreads();
      p[t] += other;
      __syncthreads();
    }
    const int carry = carry_s;
    if (c0 + t < nb) boff[c0 + t] = carry + p[t] - v;
    __syncthreads();
    if (t == 0) carry_s = carry + p[255];
    __syncthreads();
  }
}

__global__ __launch_bounds__(256) void emit_kernel(
    const int* __restrict__ cnt, const int* __restrict__ boff,
    int* __restrict__ row_ptr, int* __restrict__ row_cur, int N, int E)
{
  __shared__ int psum[256];
  const int t = threadIdx.x;
  const int base = blockIdx.x * 1024 + t * 4;
  int v[4];
  #pragma unroll
  for (int i = 0; i < 4; ++i)
    v[i] = (base + i < N) ? cnt[base + i] : 0;
  const int local = v[0] + v[1] + v[2] + v[3];
  psum[t] = local;
  __syncthreads();
  for (int off = 1; off < 256; off <<= 1) {
    const int other = (t >= off) ? psum[t - off] : 0;
    __syncthreads();
    psum[t] += other;
    __syncthreads();
  }
  int pre = boff[blockIdx.x] + psum[t] - local;
  #pragma unroll
  for (int i = 0; i < 4; ++i) {
    const int idx = base + i;
    if (idx < N) {
      row_ptr[idx] = pre;
      row_cur[idx] = pre;
      pre += v[i];
    }
  }
  if (blockIdx.x == 0 && t == 0) row_ptr[N] = E;
}

__global__ __launch_bounds__(256) void scatter_kernel(
    const int* __restrict__ rows, const int* __restrict__ cols,
    int* __restrict__ row_cur, int* __restrict__ csr_cols, int E)
{
  const int e = blockIdx.x * 256 + threadIdx.x;
  if (e >= E) return;
  const int pos = atomicAdd(&row_cur[rows[e]], 1);
  csr_cols[pos] = cols[e];
}

// ---------------------------------------------------------------------------
// Fused per-node attention + residual + LayerNorm. bf16 Q/K/V, fp32 math.
// (round-8 version verbatim — best measured: 56 µs, occupancy 70%)
// ---------------------------------------------------------------------------
__global__ __launch_bounds__(256) void fused_kernel(
    const unsigned short* __restrict__ Q, const unsigned short* __restrict__ K,
    const unsigned short* __restrict__ V, const float* __restrict__ X,
    const int* __restrict__ row_ptr, const int* __restrict__ csr_cols,
    const float* __restrict__ gamma, const float* __restrict__ beta,
    float* __restrict__ out, int N)
{
  __shared__ float lds[4][576];          // per wave: 512 V dwords + 64 ea
  const int wv = threadIdx.x >> 6;
  const int n  = blockIdx.x * 4 + wv;
  if (n >= N) return;
  const int l  = threadIdx.x & 63;
  const int h  = l & 7;    // phase-1 head
  const int g  = l >> 3;   // phase-1 edge slot
  const int hd = l >> 3;   // phase-2 head owning dims {2l, 2l+1}

  unsigned* __restrict__ Vu = reinterpret_cast<unsigned*>(lds[wv]);
  float*    __restrict__ El = lds[wv] + 512;

  float qf[16];
  {
    const unsigned short* qp = Q + (size_t)n * D_MODEL + h * HEAD_DIM;
    const bf16x8 q0 = *reinterpret_cast<const bf16x8*>(qp);
    const bf16x8 q1 = *reinterpret_cast<const bf16x8*>(qp + 8);
    #pragma unroll
    for (int i = 0; i < 8; ++i) {
      qf[i]     = b2f((unsigned short)q0[i]);
      qf[8 + i] = b2f((unsigned short)q1[i]);
    }
  }

  float accx = 0.f, accy = 0.f, dlane = 0.f;
  const int e0 = row_ptr[n];
  const int e1 = row_ptr[n + 1];

  const int rcol = (l & 7) * 64;
  const int rrot = (l >> 3) + 4 * (l & 7);

  for (int eb = e0; eb < e1; eb += 8) {
    const int  eg    = eb + g;
    const bool valid = eg < e1;
    const int  c     = valid ? csr_cols[eg] : 0;

    const unsigned short* kp = K + (size_t)c * D_MODEL + h * HEAD_DIM;
    const unsigned short* vp = V + (size_t)c * D_MODEL + h * HEAD_DIM;
    const bf16x8 k0 = *reinterpret_cast<const bf16x8*>(kp);
    const bf16x8 k1 = *reinterpret_cast<const bf16x8*>(kp + 8);
    const bf16x8 v0 = *reinterpret_cast<const bf16x8*>(vp);
    const bf16x8 v1 = *reinterpret_cast<const bf16x8*>(vp + 8);

    float s = 0.f;
    #pragma unroll
    for (int i = 0; i < 8; ++i) {
      s = fmaf(qf[i],     b2f((unsigned short)k0[i]), s);
      s = fmaf(qf[8 + i], b2f((unsigned short)k1[i]), s);
    }
    s *= 0.25f;                         // 1/sqrt(16)
    s = fminf(fmaxf(s, -10.f), 10.f);
    const float ea = valid ? __expf(s) : 0.f;
    dlane += ea;

    El[l] = ea;
    {
      const uint4 u0 = __builtin_bit_cast(uint4, v0);
      const uint4 u1 = __builtin_bit_cast(uint4, v1);
      Vu[0 * 64 + ((l +  0) & 63)] = u0.x;
      Vu[1 * 64 + ((l +  4) & 63)] = u0.y;
      Vu[2 * 64 + ((l +  8) & 63)] = u0.z;
      Vu[3 * 64 + ((l + 12) & 63)] = u0.w;
      Vu[4 * 64 + ((l + 16) & 63)] = u1.x;
      Vu[5 * 64 + ((l + 20) & 63)] = u1.y;
      Vu[6 * 64 + ((l + 24) & 63)] = u1.z;
      Vu[7 * 64 + ((l + 28) & 63)] = u1.w;
    }
    __builtin_amdgcn_sched_barrier(0);

    #pragma unroll
    for (int j = 0; j < 8; ++j) {
      const float    aj = El[j * 8 + hd];
      const unsigned vv = Vu[rcol + ((j * 8 + rrot) & 63)];
      accx = fmaf(aj, b2f((unsigned short)(vv & 0xffffu)), accx);
      accy = fmaf(aj, b2f((unsigned short)(vv >> 16)), accy);
    }
    __builtin_amdgcn_sched_barrier(0);
  }

  dlane += __shfl_xor(dlane, 8,  64);
  dlane += __shfl_xor(dlane, 16, 64);
  dlane += __shfl_xor(dlane, 32, 64);
  const float denom = __shfl(dlane, hd, 64);

  const float inv = 1.f / (denom + 1e-8f);
  const float2 x = reinterpret_cast<const float2*>(X + (size_t)n * D_MODEL)[l];
  const float a0 = accx * inv + x.x;
  const float a1 = accy * inv + x.y;

  float sm = a0 + a1;
  float ss = a0 * a0 + a1 * a1;
  #pragma unroll
  for (int off = 32; off > 0; off >>= 1) {
    sm += __shfl_xor(sm, off, 64);
    ss += __shfl_xor(ss, off, 64);
  }
  const float mean = sm * (1.f / 128.f);
  const float var  = ss * (1.f / 128.f) - mean * mean;
  const float rs   = rsqrtf(var + 1e-6f);
  const float2 gm = reinterpret_cast<const float2*>(gamma)[l];
  const float2 bt = reinterpret_cast<const float2*>(beta)[l];
  float2 o;
  o.x = (a0 - mean) * rs * gm.x + bt.x;
  o.y = (a1 - mean) * rs * gm.y + bt.y;
  reinterpret_cast<float2*>(out + (size_t)n * D_MODEL)[l] = o;
}

// ---------------------------------------------------------------------------
extern "C" void kernel_launch(void* const* d_in, const int* in_sizes, int n_in,
                              void* d_out, int out_size, void* d_ws, size_t ws_size,
                              hipStream_t stream)
{
  const float* X     = (const float*)d_in[0];
  const int*   ei    = (const int*)  d_in[1];
  const float* Wq    = (const float*)d_in[2];
  const float* bq    = (const float*)d_in[3];
  const float* Wk    = (const float*)d_in[4];
  const float* bk    = (const float*)d_in[5];
  const float* Wv    = (const float*)d_in[6];
  const float* bv    = (const float*)d_in[7];
  const float* gamma = (const float*)d_in[8];
  const float* beta  = (const float*)d_in[9];

  const int N = in_sizes[0] / D_MODEL;
  const int E = in_sizes[1] / 2;
  const int* rows = ei;
  const int* cols = ei + E;

  const size_t nd = (size_t)N * D_MODEL;
  unsigned short* Wb = (unsigned short*)d_ws;
  unsigned short* Qb = Wb + 3 * 16384;
  unsigned short* Kb = Qb + nd;
  unsigned short* Vb = Kb + nd;
  int* row_cnt  = (int*)(Vb + nd);
  int* row_ptr  = row_cnt + N;
  int* row_cur  = row_ptr + N + 1;
  int* csr_cols = row_cur + N;
  int* bsum     = csr_cols + E;
  int* boff     = bsum + ((N + 1023) / 1024) + 1;

  const int nb = (N + 1023) / 1024;

  hipMemsetAsync(row_cnt, 0, (size_t)N * sizeof(int), stream);

  cvtw_kernel<<<24, 256, 0, stream>>>(Wq, Wk, Wv, Wb);

  hist_kernel<<<(E + 255) / 256, 256, 0, stream>>>(rows, row_cnt, E);
  partial_kernel<<<nb, 256, 0, stream>>>(row_cnt, bsum, N);
  scansums_kernel<<<1, 256, 0, stream>>>(bsum, boff, nb);
  emit_kernel<<<nb, 256, 0, stream>>>(row_cnt, boff, row_ptr, row_cur, N, E);
  scatter_kernel<<<(E + 255) / 256, 256, 0, stream>>>(rows, cols, row_cur, csr_cols, E);

  qkv_mfma<<<(N + 127) / 128, 256, 0, stream>>>(
      X, Wb, bq, bk, bv, Qb, Kb, Vb, N);

  fused_kernel<<<(N + 3) / 4, 256, 0, stream>>>(
      Qb, Kb, Vb, X, row_ptr, csr_cols, gamma, beta, (float*)d_out, N);
}

// Round 13
// 138.526 us; speedup vs baseline: 1.2426x; 1.1414x over previous
//
#include <hip/hip_runtime.h>
#include <hip/hip_bf16.h>
#include <cstdint>

#define D_MODEL 128
#define N_HEADS 8
#define HEAD_DIM 16

typedef __attribute__((ext_vector_type(8))) short bf16x8;
typedef __attribute__((ext_vector_type(4))) float f32x4;

static __device__ __forceinline__ float b2f(unsigned short u) {
  unsigned int x = ((unsigned int)u) << 16;
  return __builtin_bit_cast(float, x);
}
static __device__ __forceinline__ unsigned short f2b(float f) {
  __hip_bfloat16 h = __float2bfloat16(f);   // RNE
  return __builtin_bit_cast(unsigned short, h);
}

// ---------------------------------------------------------------------------
// Merged kernel 1: blocks [0,24) convert W to bf16; blocks [24, 24+nbH) do the
// row histogram. The two jobs are data-independent -> they overlap in one
// dispatch instead of running serially as two.
// ---------------------------------------------------------------------------
__global__ __launch_bounds__(256) void hist_cvtw_kernel(
    const int* __restrict__ rows, int* __restrict__ cnt, int E,
    const float* __restrict__ Wq, const float* __restrict__ Wk,
    const float* __restrict__ Wv, unsigned short* __restrict__ Wb)
{
  if (blockIdx.x < 24) {
    const int wb = blockIdx.x;           // 24 blocks: 8 per matrix
    const int m  = wb >> 3;
    const float* src = (m == 0) ? Wq : (m == 1) ? Wk : Wv;
    unsigned short* dst = Wb + (size_t)m * 16384;
    const int base = ((wb & 7) * 256 + threadIdx.x) * 8;
    const float4 a = reinterpret_cast<const float4*>(src + base)[0];
    const float4 c = reinterpret_cast<const float4*>(src + base)[1];
    unsigned short tmp[8];
    tmp[0] = f2b(a.x); tmp[1] = f2b(a.y); tmp[2] = f2b(a.z); tmp[3] = f2b(a.w);
    tmp[4] = f2b(c.x); tmp[5] = f2b(c.y); tmp[6] = f2b(c.z); tmp[7] = f2b(c.w);
    reinterpret_cast<uint4*>(dst + base)[0] = *reinterpret_cast<uint4*>(tmp);
  } else {
    const int e = (blockIdx.x - 24) * 256 + threadIdx.x;
    if (e < E) atomicAdd(&cnt[rows[e]], 1);
  }
}

// ---------------------------------------------------------------------------
// Scan stage 1: per-1024-chunk sums.
// ---------------------------------------------------------------------------
__global__ __launch_bounds__(256) void partial_kernel(
    const int* __restrict__ cnt, int* __restrict__ bsum, int N)
{
  __shared__ int wsum[4];
  const int t = threadIdx.x;
  const int base = blockIdx.x * 1024 + t * 4;
  int s = 0;
  #pragma unroll
  for (int i = 0; i < 4; ++i)
    if (base + i < N) s += cnt[base + i];
  #pragma unroll
  for (int off = 32; off > 0; off >>= 1) s += __shfl_xor(s, off, 64);
  if ((t & 63) == 0) wsum[t >> 6] = s;
  __syncthreads();
  if (t == 0) bsum[blockIdx.x] = wsum[0] + wsum[1] + wsum[2] + wsum[3];
}

__global__ __launch_bounds__(256) void scansums_kernel(
    const int* __restrict__ bsum, int* __restrict__ boff, int nb)
{
  __shared__ int p[256];
  __shared__ int carry_s;
  const int t = threadIdx.x;
  if (t == 0) carry_s = 0;
  __syncthreads();
  for (int c0 = 0; c0 < nb; c0 += 256) {
    const int v = (c0 + t < nb) ? bsum[c0 + t] : 0;
    p[t] = v;
    __syncthreads();
    for (int off = 1; off < 256; off <<= 1) {
      const int other = (t >= off) ? p[t - off] : 0;
      __syncthreads();
      p[t] += other;
      __syncthreads();
    }
    const int carry = carry_s;
    if (c0 + t < nb) boff[c0 + t] = carry + p[t] - v;
    __syncthreads();
    if (t == 0) carry_s = carry + p[255];
    __syncthreads();
  }
}

__global__ __launch_bounds__(256) void emit_kernel(
    const int* __restrict__ cnt, const int* __restrict__ boff,
    int* __restrict__ row_ptr, int* __restrict__ row_cur, int N, int E)
{
  __shared__ int psum[256];
  const int t = threadIdx.x;
  const int base = blockIdx.x * 1024 + t * 4;
  int v[4];
  #pragma unroll
  for (int i = 0; i < 4; ++i)
    v[i] = (base + i < N) ? cnt[base + i] : 0;
  const int local = v[0] + v[1] + v[2] + v[3];
  psum[t] = local;
  __syncthreads();
  for (int off = 1; off < 256; off <<= 1) {
    const int other = (t >= off) ? psum[t - off] : 0;
    __syncthreads();
    psum[t] += other;
    __syncthreads();
  }
  int pre = boff[blockIdx.x] + psum[t] - local;
  #pragma unroll
  for (int i = 0; i < 4; ++i) {
    const int idx = base + i;
    if (idx < N) {
      row_ptr[idx] = pre;
      row_cur[idx] = pre;
      pre += v[i];
    }
  }
  if (blockIdx.x == 0 && t == 0) row_ptr[N] = E;
}

// ---------------------------------------------------------------------------
// Merged kernel 2: blocks [0, nbQ) run the MFMA QKV projection (round-11
// body: 4 waves, 128 nodes/block, W LDS-staged per m); blocks [nbQ, ...)
// run the CSR scatter. Independent jobs -> concurrent in one dispatch.
// ---------------------------------------------------------------------------
__global__ __launch_bounds__(256) void scatter_qkv_kernel(
    const int* __restrict__ rows, const int* __restrict__ cols,
    int* __restrict__ row_cur, int* __restrict__ csr_cols, int E,
    const float* __restrict__ X, const unsigned short* __restrict__ Wb,
    const float* __restrict__ bq, const float* __restrict__ bk,
    const float* __restrict__ bv,
    unsigned short* __restrict__ Qo, unsigned short* __restrict__ Ko,
    unsigned short* __restrict__ Vo, int N, int nbQ)
{
  __shared__ unsigned short Wl[128 * 128];   // used by qkv blocks only

  if ((int)blockIdx.x >= nbQ) {
    // ---------------- scatter role ----------------
    const int e = (blockIdx.x - nbQ) * 256 + threadIdx.x;
    if (e < E) {
      const int pos = atomicAdd(&row_cur[rows[e]], 1);
      csr_cols[pos] = cols[e];
    }
    return;
  }

  // ---------------- qkv role ----------------
  const int t    = threadIdx.x;
  const int wave = t >> 6;
  const int l    = t & 63;
  const int lr   = l & 15;
  const int lg   = l >> 4;
  const int nw   = blockIdx.x * 128 + wave * 32;  // first node of this wave

  bf16x8 a[2][4];
  #pragma unroll
  for (int ng = 0; ng < 2; ++ng) {
    const int arow = nw + ng * 16 + lr;
    if (arow < N) {
      const float* xp = X + (size_t)arow * D_MODEL + lg * 8;
      #pragma unroll
      for (int ks = 0; ks < 4; ++ks) {
        const float4 f0 = reinterpret_cast<const float4*>(xp + ks * 32)[0];
        const float4 f1 = reinterpret_cast<const float4*>(xp + ks * 32)[1];
        unsigned short tm[8];
        tm[0] = f2b(f0.x); tm[1] = f2b(f0.y); tm[2] = f2b(f0.z); tm[3] = f2b(f0.w);
        tm[4] = f2b(f1.x); tm[5] = f2b(f1.y); tm[6] = f2b(f1.z); tm[7] = f2b(f1.w);
        a[ng][ks] = *reinterpret_cast<bf16x8*>(tm);
      }
    } else {
      #pragma unroll
      for (int ks = 0; ks < 4; ++ks) a[ng][ks] = bf16x8{0,0,0,0,0,0,0,0};
    }
  }

  const float* biases[3] = {bq, bk, bv};
  unsigned short* outs[3] = {Qo, Ko, Vo};

  #pragma unroll 1
  for (int m = 0; m < 3; ++m) {
    __syncthreads();   // previous m's reads complete before restage
    {
      const uint4* wsrc = reinterpret_cast<const uint4*>(Wb + (size_t)m * 16384);
      uint4* wl4 = reinterpret_cast<uint4*>(Wl);
      #pragma unroll
      for (int i = 0; i < 8; ++i) {
        const int cg = i * 256 + t;          // global chunk id, 0..2047
        const int r  = cg >> 4;              // W row (output col), 0..127
        const int j  = cg & 15;              // 16B chunk within row
        wl4[r * 16 + (j ^ (r & 7))] = wsrc[cg];
      }
    }
    __syncthreads();

    unsigned short* __restrict__ O = outs[m];
    const float* __restrict__ bias = biases[m];
    float bias8[8];
    #pragma unroll
    for (int c = 0; c < 8; ++c) bias8[c] = bias[c * 16 + lr];

    #pragma unroll
    for (int c = 0; c < 8; ++c) {
      const int row = c * 16 + lr;
      bf16x8 w[4];
      #pragma unroll
      for (int ks = 0; ks < 4; ++ks) {
        const int j = ks * 4 + lg;
        w[ks] = *reinterpret_cast<const bf16x8*>(
            Wl + ((row * 16 + (j ^ (row & 7))) * 8));
      }
      #pragma unroll
      for (int ng = 0; ng < 2; ++ng) {
        f32x4 acc = {bias8[c], bias8[c], bias8[c], bias8[c]};
        #pragma unroll
        for (int ks = 0; ks < 4; ++ks)
          acc = __builtin_amdgcn_mfma_f32_16x16x32_bf16(a[ng][ks], w[ks], acc, 0, 0, 0);
        #pragma unroll
        for (int r = 0; r < 4; ++r) {
          const int orow = nw + ng * 16 + lg * 4 + r;
          if (orow < N) O[(size_t)orow * D_MODEL + c * 16 + lr] = f2b(acc[r]);
        }
      }
    }
  }
}

// ---------------------------------------------------------------------------
// Fused per-node attention + residual + LayerNorm. bf16 Q/K/V, fp32 math.
// (round-8 version verbatim — best measured: 56 µs, occupancy ~70%)
// ---------------------------------------------------------------------------
__global__ __launch_bounds__(256) void fused_kernel(
    const unsigned short* __restrict__ Q, const unsigned short* __restrict__ K,
    const unsigned short* __restrict__ V, const float* __restrict__ X,
    const int* __restrict__ row_ptr, const int* __restrict__ csr_cols,
    const float* __restrict__ gamma, const float* __restrict__ beta,
    float* __restrict__ out, int N)
{
  __shared__ float lds[4][576];          // per wave: 512 V dwords + 64 ea
  const int wv = threadIdx.x >> 6;
  const int n  = blockIdx.x * 4 + wv;
  if (n >= N) return;
  const int l  = threadIdx.x & 63;
  const int h  = l & 7;    // phase-1 head
  const int g  = l >> 3;   // phase-1 edge slot
  const int hd = l >> 3;   // phase-2 head owning dims {2l, 2l+1}

  unsigned* __restrict__ Vu = reinterpret_cast<unsigned*>(lds[wv]);
  float*    __restrict__ El = lds[wv] + 512;

  float qf[16];
  {
    const unsigned short* qp = Q + (size_t)n * D_MODEL + h * HEAD_DIM;
    const bf16x8 q0 = *reinterpret_cast<const bf16x8*>(qp);
    const bf16x8 q1 = *reinterpret_cast<const bf16x8*>(qp + 8);
    #pragma unroll
    for (int i = 0; i < 8; ++i) {
      qf[i]     = b2f((unsigned short)q0[i]);
      qf[8 + i] = b2f((unsigned short)q1[i]);
    }
  }

  float accx = 0.f, accy = 0.f, dlane = 0.f;
  const int e0 = row_ptr[n];
  const int e1 = row_ptr[n + 1];

  const int rcol = (l & 7) * 64;
  const int rrot = (l >> 3) + 4 * (l & 7);

  for (int eb = e0; eb < e1; eb += 8) {
    const int  eg    = eb + g;
    const bool valid = eg < e1;
    const int  c     = valid ? csr_cols[eg] : 0;

    const unsigned short* kp = K + (size_t)c * D_MODEL + h * HEAD_DIM;
    const unsigned short* vp = V + (size_t)c * D_MODEL + h * HEAD_DIM;
    const bf16x8 k0 = *reinterpret_cast<const bf16x8*>(kp);
    const bf16x8 k1 = *reinterpret_cast<const bf16x8*>(kp + 8);
    const bf16x8 v0 = *reinterpret_cast<const bf16x8*>(vp);
    const bf16x8 v1 = *reinterpret_cast<const bf16x8*>(vp + 8);

    float s = 0.f;
    #pragma unroll
    for (int i = 0; i < 8; ++i) {
      s = fmaf(qf[i],     b2f((unsigned short)k0[i]), s);
      s = fmaf(qf[8 + i], b2f((unsigned short)k1[i]), s);
    }
    s *= 0.25f;                         // 1/sqrt(16)
    s = fminf(fmaxf(s, -10.f), 10.f);
    const float ea = valid ? __expf(s) : 0.f;
    dlane += ea;

    El[l] = ea;
    {
      const uint4 u0 = __builtin_bit_cast(uint4, v0);
      const uint4 u1 = __builtin_bit_cast(uint4, v1);
      Vu[0 * 64 + ((l +  0) & 63)] = u0.x;
      Vu[1 * 64 + ((l +  4) & 63)] = u0.y;
      Vu[2 * 64 + ((l +  8) & 63)] = u0.z;
      Vu[3 * 64 + ((l + 12) & 63)] = u0.w;
      Vu[4 * 64 + ((l + 16) & 63)] = u1.x;
      Vu[5 * 64 + ((l + 20) & 63)] = u1.y;
      Vu[6 * 64 + ((l + 24) & 63)] = u1.z;
      Vu[7 * 64 + ((l + 28) & 63)] = u1.w;
    }
    __builtin_amdgcn_sched_barrier(0);

    #pragma unroll
    for (int j = 0; j < 8; ++j) {
      const float    aj = El[j * 8 + hd];
      const unsigned vv = Vu[rcol + ((j * 8 + rrot) & 63)];
      accx = fmaf(aj, b2f((unsigned short)(vv & 0xffffu)), accx);
      accy = fmaf(aj, b2f((unsigned short)(vv >> 16)), accy);
    }
    __builtin_amdgcn_sched_barrier(0);
  }

  dlane += __shfl_xor(dlane, 8,  64);
  dlane += __shfl_xor(dlane, 16, 64);
  dlane += __shfl_xor(dlane, 32, 64);
  const float denom = __shfl(dlane, hd, 64);

  const float inv = 1.f / (denom + 1e-8f);
  const float2 x = reinterpret_cast<const float2*>(X + (size_t)n * D_MODEL)[l];
  const float a0 = accx * inv + x.x;
  const float a1 = accy * inv + x.y;

  float sm = a0 + a1;
  float ss = a0 * a0 + a1 * a1;
  #pragma unroll
  for (int off = 32; off > 0; off >>= 1) {
    sm += __shfl_xor(sm, off, 64);
    ss += __shfl_xor(ss, off, 64);
  }
  const float mean = sm * (1.f / 128.f);
  const float var  = ss * (1.f / 128.f) - mean * mean;
  const float rs   = rsqrtf(var + 1e-6f);
  const float2 gm = reinterpret_cast<const float2*>(gamma)[l];
  const float2 bt = reinterpret_cast<const float2*>(beta)[l];
  float2 o;
  o.x = (a0 - mean) * rs * gm.x + bt.x;
  o.y = (a1 - mean) * rs * gm.y + bt.y;
  reinterpret_cast<float2*>(out + (size_t)n * D_MODEL)[l] = o;
}

// ---------------------------------------------------------------------------
extern "C" void kernel_launch(void* const* d_in, const int* in_sizes, int n_in,
                              void* d_out, int out_size, void* d_ws, size_t ws_size,
                              hipStream_t stream)
{
  const float* X     = (const float*)d_in[0];
  const int*   ei    = (const int*)  d_in[1];
  const float* Wq    = (const float*)d_in[2];
  const float* bq    = (const float*)d_in[3];
  const float* Wk    = (const float*)d_in[4];
  const float* bk    = (const float*)d_in[5];
  const float* Wv    = (const float*)d_in[6];
  const float* bv    = (const float*)d_in[7];
  const float* gamma = (const float*)d_in[8];
  const float* beta  = (const float*)d_in[9];

  const int N = in_sizes[0] / D_MODEL;
  const int E = in_sizes[1] / 2;
  const int* rows = ei;
  const int* cols = ei + E;

  const size_t nd = (size_t)N * D_MODEL;
  unsigned short* Wb = (unsigned short*)d_ws;
  unsigned short* Qb = Wb + 3 * 16384;
  unsigned short* Kb = Qb + nd;
  unsigned short* Vb = Kb + nd;
  int* row_cnt  = (int*)(Vb + nd);
  int* row_ptr  = row_cnt + N;
  int* row_cur  = row_ptr + N + 1;
  int* csr_cols = row_cur + N;
  int* bsum     = csr_cols + E;
  int* boff     = bsum + ((N + 1023) / 1024) + 1;

  const int nb  = (N + 1023) / 1024;     // scan chunks
  const int nbE = (E + 255) / 256;       // edge-parallel blocks
  const int nbQ = (N + 127) / 128;       // qkv blocks

  hipMemsetAsync(row_cnt, 0, (size_t)N * sizeof(int), stream);

  // cvtw (24 blocks) || hist (nbE blocks) in one dispatch
  hist_cvtw_kernel<<<24 + nbE, 256, 0, stream>>>(
      rows, row_cnt, E, Wq, Wk, Wv, Wb);

  partial_kernel<<<nb, 256, 0, stream>>>(row_cnt, bsum, N);
  scansums_kernel<<<1, 256, 0, stream>>>(bsum, boff, nb);
  emit_kernel<<<nb, 256, 0, stream>>>(row_cnt, boff, row_ptr, row_cur, N, E);

  // qkv (nbQ blocks, first) || scatter (nbE blocks) in one dispatch
  scatter_qkv_kernel<<<nbQ + nbE, 256, 0, stream>>>(
      rows, cols, row_cur, csr_cols, E,
      X, Wb, bq, bk, bv, Qb, Kb, Vb, N, nbQ);

  fused_kernel<<<(N + 3) / 4, 256, 0, stream>>>(
      Qb, Kb, Vb, X, row_ptr, csr_cols, gamma, beta, (float*)d_out, N);
}